// Round 6
// baseline (1958.330 us; speedup 1.0000x reference)
//
#include <hip/hip_runtime.h>
#include <hip/hip_bf16.h>

// Shapes (fixed by the reference): B=32, T=2048, D=512, H=128.
#define Bx 32
#define Tt 2048
#define Dd 512
#define Hh 128

typedef __attribute__((ext_vector_type(8))) short short8;   // 8 bf16 (4 VGPR)
typedef __attribute__((ext_vector_type(4))) float f32x4;    // MFMA C/D

static __device__ __forceinline__ short f2bf(float f) {
    __hip_bfloat16 h = __float2bfloat16(f);
    return *reinterpret_cast<short*>(&h);
}
static __device__ __forceinline__ float sigm(float x) {
    return 1.f / (1.f + __expf(-x));
}

// 16-lane-row DPP add (VALU-speed cross-lane). Stages xor1, xor2, ror4, ror8
// give a full 16-lane-row allreduce (verified numerics in R5).
template<int CTRL>
static __device__ __forceinline__ float dpp_add(float v) {
    return v + __int_as_float(__builtin_amdgcn_update_dpp(
        0, __float_as_int(v), CTRL, 0xF, 0xF, true));
}
static __device__ __forceinline__ float rowred16(float v) {
    v = dpp_add<0xB1>(v);    // quad xor1
    v = dpp_add<0x4E>(v);    // quad xor2
    v = dpp_add<0x124>(v);   // row_ror:4
    v = dpp_add<0x128>(v);   // row_ror:8
    return v;
}

// barrier that does NOT drain vmcnt (keeps G prefetch / out stores in flight)
#define BARRIER_LGKM() asm volatile("s_waitcnt lgkmcnt(0)\n\ts_barrier" ::: "memory")
// same-wave LDS write->read fence (no barrier needed within a wave)
#define WAVE_LDS_FENCE() asm volatile("s_waitcnt lgkmcnt(0)" ::: "memory")

// ---------------------------------------------------------------------------
// Phase 1: G = x @ [W_f|W_i|W_o|W_c], bf16 MFMA.  (verified R4/R5, ~80us)
// ---------------------------------------------------------------------------
__global__ __launch_bounds__(512, 2) void gemm_xw_mfma(
    const float* __restrict__ X,
    const float* __restrict__ W0, const float* __restrict__ W1,
    const float* __restrict__ W2, const float* __restrict__ W3,
    float* __restrict__ G)
{
    __shared__ __align__(16) short As[128][40];
    __shared__ __align__(16) short Bs[512][40];

    const int tid  = threadIdx.x;
    const int m0   = blockIdx.x * 128;
    const int lane = tid & 63;
    const int w    = tid >> 6;
    const int wr   = w >> 2, wc = w & 3;
    const int l15  = lane & 15, kb = lane >> 4;

    const int bn   = tid;
    const int gate = bn >> 7;
    const int j    = bn & 127;
    const float* __restrict__ Wg = (gate == 0) ? W0 : (gate == 1) ? W1 : (gate == 2) ? W2 : W3;

    const int am = tid >> 2;
    const int ak = (tid & 3) * 8;

    f32x4 acc[4][8];
    #pragma unroll
    for (int mt = 0; mt < 4; ++mt)
        #pragma unroll
        for (int nt = 0; nt < 8; ++nt)
            acc[mt][nt] = (f32x4){0.f, 0.f, 0.f, 0.f};

    for (int k0 = 0; k0 < Dd; k0 += 32) {
        {
            const float4* xp = (const float4*)&X[(size_t)(m0 + am) * Dd + k0 + ak];
            float4 v0 = xp[0], v1 = xp[1];
            short8 s;
            s[0] = f2bf(v0.x); s[1] = f2bf(v0.y); s[2] = f2bf(v0.z); s[3] = f2bf(v0.w);
            s[4] = f2bf(v1.x); s[5] = f2bf(v1.y); s[6] = f2bf(v1.z); s[7] = f2bf(v1.w);
            *(short8*)&As[am][ak] = s;
        }
        #pragma unroll
        for (int rc = 0; rc < 4; ++rc) {
            float v[8];
            #pragma unroll
            for (int r = 0; r < 8; ++r)
                v[r] = Wg[(size_t)(k0 + rc * 8 + r) * Hh + j];
            short8 s;
            #pragma unroll
            for (int r = 0; r < 8; ++r) s[r] = f2bf(v[r]);
            *(short8*)&Bs[bn][rc * 8] = s;
        }
        __syncthreads();

        short8 a[4], b[8];
        #pragma unroll
        for (int mt = 0; mt < 4; ++mt)
            a[mt] = *(const short8*)&As[wr * 64 + mt * 16 + l15][kb * 8];
        #pragma unroll
        for (int nt = 0; nt < 8; ++nt)
            b[nt] = *(const short8*)&Bs[wc * 128 + nt * 16 + l15][kb * 8];
        #pragma unroll
        for (int mt = 0; mt < 4; ++mt)
            #pragma unroll
            for (int nt = 0; nt < 8; ++nt)
                acc[mt][nt] = __builtin_amdgcn_mfma_f32_16x16x32_bf16(a[mt], b[nt], acc[mt][nt], 0, 0, 0);
        __syncthreads();
    }

    #pragma unroll
    for (int mt = 0; mt < 4; ++mt)
        #pragma unroll
        for (int nt = 0; nt < 8; ++nt)
            #pragma unroll
            for (int r = 0; r < 4; ++r)
                G[(size_t)(m0 + wr * 64 + mt * 16 + kb * 4 + r) * 512 + wc * 128 + nt * 16 + l15]
                    = acc[mt][nt][r];
}

// ---------------------------------------------------------------------------
// Phase 2: MFMA scan, gate-major wave tiling. 8 blocks x 512 threads, block
// owns 4 batches. Wave w owns j-columns w*16..w*16+15 across ALL 4 gates, so
// after MFMA the 4 gate pre-acts of (b,j) sit in the owning wave: same-wave
// LDS exchange (no barrier), DPP-row LN partials, thread-local update.
// Only 2 barriers per step (LN cross-wave combine; Ap ready).
// ---------------------------------------------------------------------------
__global__ __launch_bounds__(512, 1) void lstm_scan_mfma(
    const float* __restrict__ G,
    const float* __restrict__ Uf, const float* __restrict__ Ui,
    const float* __restrict__ Uo, const float* __restrict__ Uc,
    const float* __restrict__ bf_, const float* __restrict__ bi_,
    const float* __restrict__ bo_, const float* __restrict__ bc_,
    const float* __restrict__ lnfg, const float* __restrict__ lnfb,
    const float* __restrict__ lnig, const float* __restrict__ lnib,
    const float* __restrict__ lnog, const float* __restrict__ lnob,
    const float* __restrict__ lncg, const float* __restrict__ lncb,
    const float* __restrict__ h0, const float* __restrict__ c0,
    const int* __restrict__ zmask,
    float* __restrict__ out, float* __restrict__ hT)
{
    const int tid  = threadIdx.x;
    const int lane = tid & 63;
    const int w    = tid >> 6;          // wave 0..7
    const int b0   = blockIdx.x * 4;    // 4 batches per block
    const int l15  = lane & 15;         // jj: column within wave / B-frag col
    const int kb   = lane >> 4;         // 0..3: k-block for frags; owner batch
    const int j    = w * 16 + l15;      // owner column 0..127

    __shared__ __align__(16) short Ap[16 * 136];      // h panel bf16 [row=b][k]
    __shared__ __align__(16) float SW[8 * 4 * 16 * 4]; // [w][g][jj][b]
    __shared__ __align__(16) float red[2 * 4 * 8 * 4]; // [s][b][w] float4(g)
    __shared__ unsigned short act[Tt];
    __shared__ int wsum[8], wpre[8];
    __shared__ int nact_sh;

    // ---- B fragments: columns j of ALL FOUR U matrices (64 regs) ----
    short8 bfr[4][4];                                  // [gate][k-step]
    #pragma unroll
    for (int g = 0; g < 4; ++g) {
        const float* __restrict__ Ug = (g == 0) ? Uf : (g == 1) ? Ui : (g == 2) ? Uo : Uc;
        #pragma unroll
        for (int ks = 0; ks < 4; ++ks) {
            short8 v;
            #pragma unroll
            for (int r = 0; r < 8; ++r)
                v[r] = f2bf(Ug[(ks * 32 + kb * 8 + r) * Hh + j]);
            bfr[g][ks] = v;
        }
    }

    // ---- per-thread LN/bias constants at column j, all gates ----
    float lgam[4], lbet[4], lbias[4];
    lgam[0] = lnfg[j]; lbet[0] = lnfb[j]; lbias[0] = bf_[j];
    lgam[1] = lnig[j]; lbet[1] = lnib[j]; lbias[1] = bi_[j];
    lgam[2] = lnog[j]; lbet[2] = lnob[j]; lbias[2] = bo_[j];
    lgam[3] = lncg[j]; lbet[3] = lncb[j]; lbias[3] = bc_[j];

    // ---- owner state: thread = (batch kb, column j) ----
    float hval = h0[(b0 + kb) * Hh + j];
    float cval = c0[(b0 + kb) * Hh + j];

    for (int i = tid; i < 16 * 136; i += 512) Ap[i] = 0;
    __syncthreads();
    Ap[kb * 136 + j] = f2bf(hval);

    // ---- parallel active-list build (zmask read straight from global) ----
    {
        const int base_t = tid * 4;
        const int f0 = (zmask[base_t] == 0), f1 = (zmask[base_t + 1] == 0);
        const int f2 = (zmask[base_t + 2] == 0), f3 = (zmask[base_t + 3] == 0);
        const int cnt = f0 + f1 + f2 + f3;
        int scan = cnt;
        #pragma unroll
        for (int off = 1; off <= 32; off <<= 1) {
            int v = __shfl_up(scan, off);
            if (lane >= off) scan += v;
        }
        if (lane == 63) wsum[w] = scan;
        __syncthreads();
        if (tid == 0) {
            int s = 0;
            #pragma unroll
            for (int i = 0; i < 8; ++i) { wpre[i] = s; s += wsum[i]; }
            nact_sh = s;
        }
        __syncthreads();
        int pos = wpre[w] + scan - cnt;
        if (f0) act[pos++] = (unsigned short)(base_t);
        if (f1) act[pos++] = (unsigned short)(base_t + 1);
        if (f2) act[pos++] = (unsigned short)(base_t + 2);
        if (f3) act[pos++] = (unsigned short)(base_t + 3);
    }
    __syncthreads();
    const int nact = nact_sh;

    const int firstA = (nact > 0) ? (int)act[0] : Tt;
    for (int tt = 0; tt < firstA; ++tt)
        out[((size_t)(b0 + kb) * Tt + tt) * Hh + j] = hval;

// G prefetch for step t: C[g] frag rows = batches (row r -> b0+r)
#define PREFETCH_G(tq, DST)                                                     \
    do {                                                                        \
        const int _t = (tq);                                                    \
        DST##0[0] = G[((size_t)(b0 + 0) * Tt + _t) * 512 +   0 + j];            \
        DST##0[1] = G[((size_t)(b0 + 1) * Tt + _t) * 512 +   0 + j];            \
        DST##0[2] = G[((size_t)(b0 + 2) * Tt + _t) * 512 +   0 + j];            \
        DST##0[3] = G[((size_t)(b0 + 3) * Tt + _t) * 512 +   0 + j];            \
        DST##1[0] = G[((size_t)(b0 + 0) * Tt + _t) * 512 + 128 + j];            \
        DST##1[1] = G[((size_t)(b0 + 1) * Tt + _t) * 512 + 128 + j];            \
        DST##1[2] = G[((size_t)(b0 + 2) * Tt + _t) * 512 + 128 + j];            \
        DST##1[3] = G[((size_t)(b0 + 3) * Tt + _t) * 512 + 128 + j];            \
        DST##2[0] = G[((size_t)(b0 + 0) * Tt + _t) * 512 + 256 + j];            \
        DST##2[1] = G[((size_t)(b0 + 1) * Tt + _t) * 512 + 256 + j];            \
        DST##2[2] = G[((size_t)(b0 + 2) * Tt + _t) * 512 + 256 + j];            \
        DST##2[3] = G[((size_t)(b0 + 3) * Tt + _t) * 512 + 256 + j];            \
        DST##3[0] = G[((size_t)(b0 + 0) * Tt + _t) * 512 + 384 + j];            \
        DST##3[1] = G[((size_t)(b0 + 1) * Tt + _t) * 512 + 384 + j];            \
        DST##3[2] = G[((size_t)(b0 + 2) * Tt + _t) * 512 + 384 + j];            \
        DST##3[3] = G[((size_t)(b0 + 3) * Tt + _t) * 512 + 384 + j];            \
    } while (0)

    f32x4 gA0, gA1, gA2, gA3, gB0, gB1, gB2, gB3;
    if (nact > 0) PREFETCH_G((int)act[0], gA);
    if (nact > 1) PREFETCH_G((int)act[1], gB);

#define LSTM_STEP(KK, CUR)                                                      \
    do {                                                                        \
        const int _k  = (KK);                                                   \
        const int _t  = (int)act[_k];                                           \
        const int _t2 = (_k + 1 < nact) ? (int)act[_k + 1] : Tt;                \
        /* ---- S = h @ U + G : 4 independent g-chains, depth 4 ---- */         \
        short8 _a0 = *(const short8*)&Ap[l15 * 136 +  0 + kb * 8];              \
        short8 _a1 = *(const short8*)&Ap[l15 * 136 + 32 + kb * 8];              \
        short8 _a2 = *(const short8*)&Ap[l15 * 136 + 64 + kb * 8];              \
        short8 _a3 = *(const short8*)&Ap[l15 * 136 + 96 + kb * 8];              \
        f32x4 _C0 = CUR##0, _C1 = CUR##1, _C2 = CUR##2, _C3 = CUR##3;           \
        _C0 = __builtin_amdgcn_mfma_f32_16x16x32_bf16(_a0, bfr[0][0], _C0, 0,0,0); \
        _C1 = __builtin_amdgcn_mfma_f32_16x16x32_bf16(_a0, bfr[1][0], _C1, 0,0,0); \
        _C2 = __builtin_amdgcn_mfma_f32_16x16x32_bf16(_a0, bfr[2][0], _C2, 0,0,0); \
        _C3 = __builtin_amdgcn_mfma_f32_16x16x32_bf16(_a0, bfr[3][0], _C3, 0,0,0); \
        _C0 = __builtin_amdgcn_mfma_f32_16x16x32_bf16(_a1, bfr[0][1], _C0, 0,0,0); \
        _C1 = __builtin_amdgcn_mfma_f32_16x16x32_bf16(_a1, bfr[1][1], _C1, 0,0,0); \
        _C2 = __builtin_amdgcn_mfma_f32_16x16x32_bf16(_a1, bfr[2][1], _C2, 0,0,0); \
        _C3 = __builtin_amdgcn_mfma_f32_16x16x32_bf16(_a1, bfr[3][1], _C3, 0,0,0); \
        _C0 = __builtin_amdgcn_mfma_f32_16x16x32_bf16(_a2, bfr[0][2], _C0, 0,0,0); \
        _C1 = __builtin_amdgcn_mfma_f32_16x16x32_bf16(_a2, bfr[1][2], _C1, 0,0,0); \
        _C2 = __builtin_amdgcn_mfma_f32_16x16x32_bf16(_a2, bfr[2][2], _C2, 0,0,0); \
        _C3 = __builtin_amdgcn_mfma_f32_16x16x32_bf16(_a2, bfr[3][2], _C3, 0,0,0); \
        _C0 = __builtin_amdgcn_mfma_f32_16x16x32_bf16(_a3, bfr[0][3], _C0, 0,0,0); \
        _C1 = __builtin_amdgcn_mfma_f32_16x16x32_bf16(_a3, bfr[1][3], _C1, 0,0,0); \
        _C2 = __builtin_amdgcn_mfma_f32_16x16x32_bf16(_a3, bfr[2][3], _C2, 0,0,0); \
        _C3 = __builtin_amdgcn_mfma_f32_16x16x32_bf16(_a3, bfr[3][3], _C3, 0,0,0); \
        if (_k + 2 < nact) PREFETCH_G((int)act[_k + 2], CUR);                   \
        /* ---- same-wave exchange: rows 0..3 (kb==0 lanes) hold batches ---- */\
        if (lane < 16) {                                                        \
            *(float4*)&SW[w * 256 +   0 + l15 * 4] = make_float4(_C0[0], _C0[1], _C0[2], _C0[3]); \
            *(float4*)&SW[w * 256 +  64 + l15 * 4] = make_float4(_C1[0], _C1[1], _C1[2], _C1[3]); \
            *(float4*)&SW[w * 256 + 128 + l15 * 4] = make_float4(_C2[0], _C2[1], _C2[2], _C2[3]); \
            *(float4*)&SW[w * 256 + 192 + l15 * 4] = make_float4(_C3[0], _C3[1], _C3[2], _C3[3]); \
        }                                                                       \
        WAVE_LDS_FENCE();                                                       \
        /* ---- owner thread (kb, j) pulls its 4 gate pre-acts ---- */          \
        float _s[4], _sm[4], _sq[4];                                            \
        _s[0] = SW[w * 256 +   0 + l15 * 4 + kb] + lbias[0];                    \
        _s[1] = SW[w * 256 +  64 + l15 * 4 + kb] + lbias[1];                    \
        _s[2] = SW[w * 256 + 128 + l15 * 4 + kb] + lbias[2];                    \
        _s[3] = SW[w * 256 + 192 + l15 * 4 + kb] + lbias[3];                    \
        _Pragma("unroll")                                                       \
        for (int _g = 0; _g < 4; ++_g) {                                        \
            _sm[_g] = rowred16(_s[_g]);                                         \
            _sq[_g] = rowred16(_s[_g] * _s[_g]);                                \
        }                                                                       \
        if (l15 == 0) {                                                         \
            *(float4*)&red[(0 * 4 + kb) * 32 + w * 4] = make_float4(_sm[0], _sm[1], _sm[2], _sm[3]); \
            *(float4*)&red[(1 * 4 + kb) * 32 + w * 4] = make_float4(_sq[0], _sq[1], _sq[2], _sq[3]); \
        }                                                                       \
        BARRIER_LGKM();                                                         \
        /* ---- cross-wave combine: lanes jj read wave jj&7, row-reduce ---- */ \
        f32x4 _ps = *(const f32x4*)&red[(0 * 4 + kb) * 32 + (l15 & 7) * 4];     \
        f32x4 _pq = *(const f32x4*)&red[(1 * 4 + kb) * 32 + (l15 & 7) * 4];     \
        _Pragma("unroll")                                                       \
        for (int _g = 0; _g < 4; ++_g) {                                        \
            _ps[_g] = rowred16(_ps[_g]);                                        \
            _pq[_g] = rowred16(_pq[_g]);                                        \
        }                                                                       \
        float _v[4];                                                            \
        _Pragma("unroll")                                                       \
        for (int _g = 0; _g < 4; ++_g) {                                        \
            const float _mu   = _ps[_g] * (1.f / 256.f);  /* each w counted 2x */ \
            const float _rstd = rsqrtf(_pq[_g] * (1.f / 256.f) - _mu * _mu + 1e-5f); \
            _v[_g] = sigm((_s[_g] - _mu) * _rstd * lgam[_g] + lbet[_g]);        \
        }                                                                       \
        cval = _v[0] * cval + _v[1] * _v[3];                                    \
        hval = _v[2] * sigm(cval);          /* NB: sigmoid, not tanh */         \
        Ap[kb * 136 + j] = f2bf(hval);                                          \
        for (int _tt = _t; _tt < _t2; ++_tt)                                    \
            out[((size_t)(b0 + kb) * Tt + _tt) * Hh + j] = hval;                \
        BARRIER_LGKM();                                                         \
    } while (0)

    for (int k = 0; k < nact; k += 2) {
        LSTM_STEP(k, gA);
        if (k + 1 < nact) LSTM_STEP(k + 1, gB);
    }

    hT[(b0 + kb) * Hh + j] = hval;
#undef LSTM_STEP
#undef PREFETCH_G
}

// ---------------------------------------------------------------------------
extern "C" void kernel_launch(void* const* d_in, const int* in_sizes, int n_in,
                              void* d_out, int out_size, void* d_ws, size_t ws_size,
                              hipStream_t stream)
{
    const float* x   = (const float*)d_in[0];
    const float* W_f = (const float*)d_in[1];
    const float* W_i = (const float*)d_in[2];
    const float* W_o = (const float*)d_in[3];
    const float* W_c = (const float*)d_in[4];
    const float* U_f = (const float*)d_in[5];
    const float* U_i = (const float*)d_in[6];
    const float* U_o = (const float*)d_in[7];
    const float* U_c = (const float*)d_in[8];
    const float* b_f = (const float*)d_in[9];
    const float* b_i = (const float*)d_in[10];
    const float* b_o = (const float*)d_in[11];
    const float* b_c = (const float*)d_in[12];
    const float* ln_f_g = (const float*)d_in[13];
    const float* ln_f_b = (const float*)d_in[14];
    const float* ln_i_g = (const float*)d_in[15];
    const float* ln_i_b = (const float*)d_in[16];
    const float* ln_o_g = (const float*)d_in[17];
    const float* ln_o_b = (const float*)d_in[18];
    const float* ln_c_g = (const float*)d_in[19];
    const float* ln_c_b = (const float*)d_in[20];
    const float* h0  = (const float*)d_in[21];
    const float* c0  = (const float*)d_in[22];
    const int*   zm  = (const int*)d_in[23];

    float* out = (float*)d_out;                       // [B, T, H]
    float* hT  = out + (size_t)Bx * Tt * Hh;          // [B, H]
    float* G   = (float*)d_ws;                        // [B*T, 512] = 128 MiB

    gemm_xw_mfma<<<(Bx * Tt) / 128, 512, 0, stream>>>(x, W_f, W_i, W_o, W_c, G);

    lstm_scan_mfma<<<8, 512, 0, stream>>>(G, U_f, U_i, U_o, U_c,
                                          b_f, b_i, b_o, b_c,
                                          ln_f_g, ln_f_b, ln_i_g, ln_i_b,
                                          ln_o_g, ln_o_b, ln_c_g, ln_c_b,
                                          h0, c0, zm, out, hT);
}

// Round 7
// 1651.172 us; speedup vs baseline: 1.1860x; 1.1860x over previous
//
#include <hip/hip_runtime.h>
#include <hip/hip_bf16.h>

// Shapes (fixed by the reference): B=32, T=2048, D=512, H=128.
#define Bx 32
#define Tt 2048
#define Dd 512
#define Hh 128

typedef __attribute__((ext_vector_type(8))) short short8;   // 8 bf16 (4 VGPR)
typedef __attribute__((ext_vector_type(4))) float f32x4;    // MFMA C/D

static __device__ __forceinline__ short f2bf(float f) {
    __hip_bfloat16 h = __float2bfloat16(f);
    return *reinterpret_cast<short*>(&h);
}
static __device__ __forceinline__ float sigm(float x) {
    return 1.f / (1.f + __expf(-x));
}

// 16-lane-row DPP add stages (verified R5): xor1, xor2, ror4, ror8
template<int CTRL>
static __device__ __forceinline__ float dpp_add(float v) {
    return v + __int_as_float(__builtin_amdgcn_update_dpp(
        0, __float_as_int(v), CTRL, 0xF, 0xF, true));
}
static __device__ __forceinline__ float swz_xor16_add(float v) {
    return v + __int_as_float(__builtin_amdgcn_ds_swizzle(__float_as_int(v), 0x401F));
}

// barrier that does NOT drain vmcnt
#define BARRIER_LGKM() asm volatile("s_waitcnt lgkmcnt(0)\n\ts_barrier" ::: "memory")

// async global->LDS, 16B per lane: LDS dest = uniform base + lane*16
typedef __attribute__((address_space(1))) const void gas_void;
typedef __attribute__((address_space(3))) void las_void;
static __device__ __forceinline__ void gl_lds16(const float* g, float* l) {
    __builtin_amdgcn_global_load_lds((gas_void*)g, (las_void*)l, 16, 0, 0);
}

// ---------------------------------------------------------------------------
// Phase 1: G = x @ [W_f|W_i|W_o|W_c], bf16 MFMA.  (verified R4/R5, ~90us)
// ---------------------------------------------------------------------------
__global__ __launch_bounds__(512, 2) void gemm_xw_mfma(
    const float* __restrict__ X,
    const float* __restrict__ W0, const float* __restrict__ W1,
    const float* __restrict__ W2, const float* __restrict__ W3,
    float* __restrict__ G)
{
    __shared__ __align__(16) short As[128][40];
    __shared__ __align__(16) short Bs[512][40];

    const int tid  = threadIdx.x;
    const int m0   = blockIdx.x * 128;
    const int lane = tid & 63;
    const int w    = tid >> 6;
    const int wr   = w >> 2, wc = w & 3;
    const int l15  = lane & 15, kb = lane >> 4;

    const int bn   = tid;
    const int gate = bn >> 7;
    const int j    = bn & 127;
    const float* __restrict__ Wg = (gate == 0) ? W0 : (gate == 1) ? W1 : (gate == 2) ? W2 : W3;

    const int am = tid >> 2;
    const int ak = (tid & 3) * 8;

    f32x4 acc[4][8];
    #pragma unroll
    for (int mt = 0; mt < 4; ++mt)
        #pragma unroll
        for (int nt = 0; nt < 8; ++nt)
            acc[mt][nt] = (f32x4){0.f, 0.f, 0.f, 0.f};

    for (int k0 = 0; k0 < Dd; k0 += 32) {
        {
            const float4* xp = (const float4*)&X[(size_t)(m0 + am) * Dd + k0 + ak];
            float4 v0 = xp[0], v1 = xp[1];
            short8 s;
            s[0] = f2bf(v0.x); s[1] = f2bf(v0.y); s[2] = f2bf(v0.z); s[3] = f2bf(v0.w);
            s[4] = f2bf(v1.x); s[5] = f2bf(v1.y); s[6] = f2bf(v1.z); s[7] = f2bf(v1.w);
            *(short8*)&As[am][ak] = s;
        }
        #pragma unroll
        for (int rc = 0; rc < 4; ++rc) {
            float v[8];
            #pragma unroll
            for (int r = 0; r < 8; ++r)
                v[r] = Wg[(size_t)(k0 + rc * 8 + r) * Hh + j];
            short8 s;
            #pragma unroll
            for (int r = 0; r < 8; ++r) s[r] = f2bf(v[r]);
            *(short8*)&Bs[bn][rc * 8] = s;
        }
        __syncthreads();

        short8 a[4], b[8];
        #pragma unroll
        for (int mt = 0; mt < 4; ++mt)
            a[mt] = *(const short8*)&As[wr * 64 + mt * 16 + l15][kb * 8];
        #pragma unroll
        for (int nt = 0; nt < 8; ++nt)
            b[nt] = *(const short8*)&Bs[wc * 128 + nt * 16 + l15][kb * 8];
        #pragma unroll
        for (int mt = 0; mt < 4; ++mt)
            #pragma unroll
            for (int nt = 0; nt < 8; ++nt)
                acc[mt][nt] = __builtin_amdgcn_mfma_f32_16x16x32_bf16(a[mt], b[nt], acc[mt][nt], 0, 0, 0);
        __syncthreads();
    }

    #pragma unroll
    for (int mt = 0; mt < 4; ++mt)
        #pragma unroll
        for (int nt = 0; nt < 8; ++nt)
            #pragma unroll
            for (int r = 0; r < 4; ++r)
                G[(size_t)(m0 + wr * 64 + mt * 16 + kb * 4 + r) * 512 + wc * 128 + nt * 16 + l15]
                    = acc[mt][nt][r];
}

// ---------------------------------------------------------------------------
// Phase 2: MFMA scan, R5 structure (verified) + static vmem:
// - exactly ONE global store per active step (zoneout rows filled later)
// - G staged via global_load_lds into 4-step LDS panels, double-buffered;
//   one explicit vmcnt(0) per 4 steps instead of per-step drains.
// ---------------------------------------------------------------------------
__global__ __launch_bounds__(512, 1) void lstm_scan_mfma(
    const float* __restrict__ G,
    const float* __restrict__ Uf, const float* __restrict__ Ui,
    const float* __restrict__ Uo, const float* __restrict__ Uc,
    const float* __restrict__ bf_, const float* __restrict__ bi_,
    const float* __restrict__ bo_, const float* __restrict__ bc_,
    const float* __restrict__ lnfg, const float* __restrict__ lnfb,
    const float* __restrict__ lnig, const float* __restrict__ lnib,
    const float* __restrict__ lnog, const float* __restrict__ lnob,
    const float* __restrict__ lncg, const float* __restrict__ lncb,
    const float* __restrict__ h0, const float* __restrict__ c0,
    const int* __restrict__ zmask,
    float* __restrict__ out, float* __restrict__ hT)
{
    const int tid  = threadIdx.x;
    const int lane = tid & 63;
    const int w    = tid >> 6;          // wave 0..7
    const int b0   = blockIdx.x * 4;    // 4 batches per block

    __shared__ __align__(16) short Ap[16 * 136];     // h panel bf16 [row=b][k]
    __shared__ __align__(16) float ST[512 * 10];     // S/gates transposed [col][b]
    __shared__ __align__(16) float Pan[2 * 4 * 4 * 512]; // [buf][slot][b][col] 64KB
    __shared__ unsigned short act[Tt];
    __shared__ int wsum[8], wpre[8];
    __shared__ int nact_sh;

    // ---- B fragments: U columns in bf16 (wave w -> gate w>>1, 64 cols) ----
    const int gate = w >> 1;
    const float* __restrict__ Ug = (gate == 0) ? Uf : (gate == 1) ? Ui : (gate == 2) ? Uo : Uc;
    const int n0  = w * 64;
    const int l15 = lane & 15;
    const int kb  = lane >> 4;

    short8 bfr[4][4];
    #pragma unroll
    for (int nt = 0; nt < 4; ++nt) {
        const int jloc = (n0 & 127) + nt * 16 + l15;
        #pragma unroll
        for (int ks = 0; ks < 4; ++ks) {
            short8 v;
            #pragma unroll
            for (int r = 0; r < 8; ++r)
                v[r] = f2bf(Ug[(ks * 32 + kb * 8 + r) * Hh + jloc]);
            bfr[nt][ks] = v;
        }
    }

    // ---- LN-thread constants: thread = (rowL = bL*4+gL, cl) ----
    const int rowL = tid >> 5;
    const int bL   = rowL >> 2;
    const int gL   = rowL & 3;
    const int cl   = tid & 31;
    const float* lnGp = (gL == 0) ? lnfg : (gL == 1) ? lnig : (gL == 2) ? lnog : lncg;
    const float* lnBp = (gL == 0) ? lnfb : (gL == 1) ? lnib : (gL == 2) ? lnob : lncb;
    const float* bgp  = (gL == 0) ? bf_  : (gL == 1) ? bi_  : (gL == 2) ? bo_  : bc_;
    float lgam[4], lbet[4], lbias[4];
    #pragma unroll
    for (int kk = 0; kk < 4; ++kk) {
        const int jc = cl + 32 * kk;
        lgam[kk] = lnGp[jc]; lbet[kk] = lnBp[jc]; lbias[kk] = bgp[jc];
    }

    // ---- owner state: thread = (ob = tid>>7, oj = tid&127) ----
    const int ob = tid >> 7;
    const int oj = tid & 127;
    float hval = h0[(b0 + ob) * Hh + oj];
    float cval = c0[(b0 + ob) * Hh + oj];

    for (int i = tid; i < 16 * 136; i += 512) Ap[i] = 0;
    __syncthreads();
    Ap[ob * 136 + oj] = f2bf(hval);

    // ---- parallel active-list build ----
    {
        const int base_t = tid * 4;
        const int f0 = (zmask[base_t] == 0), f1 = (zmask[base_t + 1] == 0);
        const int f2 = (zmask[base_t + 2] == 0), f3 = (zmask[base_t + 3] == 0);
        const int cnt = f0 + f1 + f2 + f3;
        int scan = cnt;
        #pragma unroll
        for (int off = 1; off <= 32; off <<= 1) {
            int v = __shfl_up(scan, off);
            if (lane >= off) scan += v;
        }
        if (lane == 63) wsum[w] = scan;
        __syncthreads();
        if (tid == 0) {
            int s = 0;
            #pragma unroll
            for (int i = 0; i < 8; ++i) { wpre[i] = s; s += wsum[i]; }
            nact_sh = s;
        }
        __syncthreads();
        int pos = wpre[w] + scan - cnt;
        if (f0) act[pos++] = (unsigned short)(base_t);
        if (f1) act[pos++] = (unsigned short)(base_t + 1);
        if (f2) act[pos++] = (unsigned short)(base_t + 2);
        if (f3) act[pos++] = (unsigned short)(base_t + 3);
    }
    __syncthreads();
    const int nact = nact_sh;

    // ---- G panel staging: wave w loads slices {2w, 2w+1}; slice = slot*4+b,
    //      2KB each = 2 x (64 lanes x 16B) DMA instructions ----
    auto stage_panel = [&](int kp, int buf) {
        #pragma unroll
        for (int si = 0; si < 2; ++si) {
            const int s    = w * 2 + si;
            const int slot = s >> 2;
            const int bb   = s & 3;
            const int kidx = kp + slot;
            if (kidx < nact) {
                const int tt = (int)act[kidx];
                const float* src = &G[((size_t)(b0 + bb) * Tt + tt) * 512];
                float* dst = &Pan[((buf * 4 + slot) * 4 + bb) * 512];
                gl_lds16(src + lane * 4, dst);
                gl_lds16(src + 256 + lane * 4, dst + 256);
            }
        }
    };

    int cur = 0;
    stage_panel(0, 0);
    asm volatile("s_waitcnt vmcnt(0)" ::: "memory");
    __syncthreads();

    auto lstm_step = [&](int kidx, int slot) {
        const int t_ = (int)act[kidx];

        // G from panel (broadcast reads: kb-lanes share addresses)
        float Gv[4][4];
        #pragma unroll
        for (int nt = 0; nt < 4; ++nt)
            #pragma unroll
            for (int r = 0; r < 4; ++r)
                Gv[nt][r] = Pan[((cur * 4 + slot) * 4 + r) * 512 + n0 + nt * 16 + l15];

        short8 a0 = *(const short8*)&Ap[l15 * 136 +  0 + kb * 8];
        short8 a1 = *(const short8*)&Ap[l15 * 136 + 32 + kb * 8];
        short8 a2 = *(const short8*)&Ap[l15 * 136 + 64 + kb * 8];
        short8 a3 = *(const short8*)&Ap[l15 * 136 + 96 + kb * 8];

        f32x4 C0 = {Gv[0][0], Gv[0][1], Gv[0][2], Gv[0][3]};
        f32x4 C1 = {Gv[1][0], Gv[1][1], Gv[1][2], Gv[1][3]};
        f32x4 C2 = {Gv[2][0], Gv[2][1], Gv[2][2], Gv[2][3]};
        f32x4 C3 = {Gv[3][0], Gv[3][1], Gv[3][2], Gv[3][3]};

        C0 = __builtin_amdgcn_mfma_f32_16x16x32_bf16(a0, bfr[0][0], C0, 0, 0, 0);
        C1 = __builtin_amdgcn_mfma_f32_16x16x32_bf16(a0, bfr[1][0], C1, 0, 0, 0);
        C2 = __builtin_amdgcn_mfma_f32_16x16x32_bf16(a0, bfr[2][0], C2, 0, 0, 0);
        C3 = __builtin_amdgcn_mfma_f32_16x16x32_bf16(a0, bfr[3][0], C3, 0, 0, 0);
        C0 = __builtin_amdgcn_mfma_f32_16x16x32_bf16(a1, bfr[0][1], C0, 0, 0, 0);
        C1 = __builtin_amdgcn_mfma_f32_16x16x32_bf16(a1, bfr[1][1], C1, 0, 0, 0);
        C2 = __builtin_amdgcn_mfma_f32_16x16x32_bf16(a1, bfr[2][1], C2, 0, 0, 0);
        C3 = __builtin_amdgcn_mfma_f32_16x16x32_bf16(a1, bfr[3][1], C3, 0, 0, 0);
        C0 = __builtin_amdgcn_mfma_f32_16x16x32_bf16(a2, bfr[0][2], C0, 0, 0, 0);
        C1 = __builtin_amdgcn_mfma_f32_16x16x32_bf16(a2, bfr[1][2], C1, 0, 0, 0);
        C2 = __builtin_amdgcn_mfma_f32_16x16x32_bf16(a2, bfr[2][2], C2, 0, 0, 0);
        C3 = __builtin_amdgcn_mfma_f32_16x16x32_bf16(a2, bfr[3][2], C3, 0, 0, 0);
        C0 = __builtin_amdgcn_mfma_f32_16x16x32_bf16(a3, bfr[0][3], C0, 0, 0, 0);
        C1 = __builtin_amdgcn_mfma_f32_16x16x32_bf16(a3, bfr[1][3], C1, 0, 0, 0);
        C2 = __builtin_amdgcn_mfma_f32_16x16x32_bf16(a3, bfr[2][3], C2, 0, 0, 0);
        C3 = __builtin_amdgcn_mfma_f32_16x16x32_bf16(a3, bfr[3][3], C3, 0, 0, 0);

        if (lane < 16) {
            *(float2*)&ST[(n0 +  0 + l15) * 10]     = make_float2(C0[0], C0[1]);
            *(float2*)&ST[(n0 +  0 + l15) * 10 + 2] = make_float2(C0[2], C0[3]);
            *(float2*)&ST[(n0 + 16 + l15) * 10]     = make_float2(C1[0], C1[1]);
            *(float2*)&ST[(n0 + 16 + l15) * 10 + 2] = make_float2(C1[2], C1[3]);
            *(float2*)&ST[(n0 + 32 + l15) * 10]     = make_float2(C2[0], C2[1]);
            *(float2*)&ST[(n0 + 32 + l15) * 10 + 2] = make_float2(C2[2], C2[3]);
            *(float2*)&ST[(n0 + 48 + l15) * 10]     = make_float2(C3[0], C3[1]);
            *(float2*)&ST[(n0 + 48 + l15) * 10 + 2] = make_float2(C3[2], C3[3]);
        }
        BARRIER_LGKM();

        // LayerNorm + sigmoid (R5-verified: local-4 sums + one 32-lane reduce)
        float s0_ = ST[(gL * 128 + cl +  0) * 10 + bL] + lbias[0];
        float s1_ = ST[(gL * 128 + cl + 32) * 10 + bL] + lbias[1];
        float s2_ = ST[(gL * 128 + cl + 64) * 10 + bL] + lbias[2];
        float s3_ = ST[(gL * 128 + cl + 96) * 10 + bL] + lbias[3];
        float sm = (s0_ + s1_) + (s2_ + s3_);
        float sq = s0_ * s0_ + s1_ * s1_ + s2_ * s2_ + s3_ * s3_;
        sm = dpp_add<0xB1>(sm);  sq = dpp_add<0xB1>(sq);
        sm = dpp_add<0x4E>(sm);  sq = dpp_add<0x4E>(sq);
        sm = dpp_add<0x124>(sm); sq = dpp_add<0x124>(sq);
        sm = dpp_add<0x128>(sm); sq = dpp_add<0x128>(sq);
        sm = swz_xor16_add(sm);  sq = swz_xor16_add(sq);
        const float mu   = sm * (1.f / 128.f);
        const float rstd = rsqrtf(sq * (1.f / 128.f) - mu * mu + 1e-5f);
        ST[(gL * 128 + cl +  0) * 10 + bL] = sigm((s0_ - mu) * rstd * lgam[0] + lbet[0]);
        ST[(gL * 128 + cl + 32) * 10 + bL] = sigm((s1_ - mu) * rstd * lgam[1] + lbet[1]);
        ST[(gL * 128 + cl + 64) * 10 + bL] = sigm((s2_ - mu) * rstd * lgam[2] + lbet[2]);
        ST[(gL * 128 + cl + 96) * 10 + bL] = sigm((s3_ - mu) * rstd * lgam[3] + lbet[3]);
        BARRIER_LGKM();

        // owner update: exactly ONE global store
        const float gf  = ST[(0   + oj) * 10 + ob];
        const float gi  = ST[(128 + oj) * 10 + ob];
        const float go  = ST[(256 + oj) * 10 + ob];
        const float gch = ST[(384 + oj) * 10 + ob];
        cval = gf * cval + gi * gch;
        hval = go * sigm(cval);                      // NB: sigmoid, not tanh
        Ap[ob * 136 + oj] = f2bf(hval);
        out[((size_t)(b0 + ob) * Tt + t_) * Hh + oj] = hval;
    };

    for (int kp = 0; kp < nact; kp += 4) {
        stage_panel(kp + 4, cur ^ 1);                // issue next panel early
        const int lim = (nact - kp < 4) ? (nact - kp) : 4;
        #pragma unroll
        for (int sl = 0; sl < 4; ++sl) {
            if (sl < lim) {
                lstm_step(kp + sl, sl);
                if (sl == 3)                          // once per group: drain
                    asm volatile("s_waitcnt vmcnt(0)" ::: "memory");
                BARRIER_LGKM();
            }
        }
        cur ^= 1;
    }

    hT[(b0 + ob) * Hh + oj] = hval;
}

// ---------------------------------------------------------------------------
// Phase 3: fill zoneout timesteps: out[:,t,:] = out[:,src,:] (src = previous
// active step) or h0 if none. Scan wrote only active steps.
// ---------------------------------------------------------------------------
__global__ __launch_bounds__(512) void fill_zoneout(
    const int* __restrict__ zmask, const float* __restrict__ h0,
    float* __restrict__ out)
{
    const int t = blockIdx.x;
    if (zmask[t] == 0) return;            // active: scan wrote it
    int s = t - 1;
    while (s >= 0 && zmask[s] != 0) --s;  // short expected walk (L1-hot)
    const int tid = threadIdx.x;
    for (int idx = tid; idx < Bx * Hh; idx += 512) {
        const int b = idx >> 7, j = idx & 127;
        const float v = (s >= 0) ? out[((size_t)b * Tt + s) * Hh + j]
                                 : h0[b * Hh + j];
        out[((size_t)b * Tt + t) * Hh + j] = v;
    }
}

// ---------------------------------------------------------------------------
extern "C" void kernel_launch(void* const* d_in, const int* in_sizes, int n_in,
                              void* d_out, int out_size, void* d_ws, size_t ws_size,
                              hipStream_t stream)
{
    const float* x   = (const float*)d_in[0];
    const float* W_f = (const float*)d_in[1];
    const float* W_i = (const float*)d_in[2];
    const float* W_o = (const float*)d_in[3];
    const float* W_c = (const float*)d_in[4];
    const float* U_f = (const float*)d_in[5];
    const float* U_i = (const float*)d_in[6];
    const float* U_o = (const float*)d_in[7];
    const float* U_c = (const float*)d_in[8];
    const float* b_f = (const float*)d_in[9];
    const float* b_i = (const float*)d_in[10];
    const float* b_o = (const float*)d_in[11];
    const float* b_c = (const float*)d_in[12];
    const float* ln_f_g = (const float*)d_in[13];
    const float* ln_f_b = (const float*)d_in[14];
    const float* ln_i_g = (const float*)d_in[15];
    const float* ln_i_b = (const float*)d_in[16];
    const float* ln_o_g = (const float*)d_in[17];
    const float* ln_o_b = (const float*)d_in[18];
    const float* ln_c_g = (const float*)d_in[19];
    const float* ln_c_b = (const float*)d_in[20];
    const float* h0  = (const float*)d_in[21];
    const float* c0  = (const float*)d_in[22];
    const int*   zm  = (const int*)d_in[23];

    float* out = (float*)d_out;                       // [B, T, H]
    float* hT  = out + (size_t)Bx * Tt * Hh;          // [B, H]
    float* G   = (float*)d_ws;                        // [B*T, 512] = 128 MiB

    gemm_xw_mfma<<<(Bx * Tt) / 128, 512, 0, stream>>>(x, W_f, W_i, W_o, W_c, G);

    lstm_scan_mfma<<<8, 512, 0, stream>>>(G, U_f, U_i, U_o, U_c,
                                          b_f, b_i, b_o, b_c,
                                          ln_f_g, ln_f_b, ln_i_g, ln_i_b,
                                          ln_o_g, ln_o_b, ln_c_g, ln_c_b,
                                          h0, c0, zm, out, hT);

    fill_zoneout<<<Tt, 512, 0, stream>>>(zm, h0, out);
}